// Round 13
// baseline (538.329 us; speedup 1.0000x reference)
//
#include <hip/hip_runtime.h>
#include <hip/hip_bf16.h>

typedef __attribute__((ext_vector_type(4))) float f32x4;
typedef __attribute__((ext_vector_type(8))) short short8;

#define B_   32
#define S_   2048
#define H_   1024
#define D2_  2048   // 2H
#define BM   256
#define BN   256
#define BK   32
#define NKT  64        // D2_/BK
#define TILE_SH 8192   // shorts per 256x32 tile (16 KB)

// Tile image layout (keys_bf [mt 256][kts 64], uab_t [nt 4][kts 64]): per tile
// 256 rows x 4 slots x 16B; slot s' holds k-quarter q = s' ^ ((row>>1)&3);
// global k = kts*32 + q*8 + e.

// RNE f32 -> bf16
__device__ __forceinline__ short f2bf(float f) {
  unsigned u = __float_as_uint(f);
  u = (u + 0x7fffu + ((u >> 16) & 1u)) >> 16;
  return (short)u;
}

__device__ __forceinline__ float bf2f(short s) {
  return __uint_as_float(((unsigned)(unsigned short)s) << 16);
}

__device__ __forceinline__ short8 cvt8(f32x4 a, f32x4 b) {
  short8 o;
  o[0] = f2bf(a.x); o[1] = f2bf(a.y); o[2] = f2bf(a.z); o[3] = f2bf(a.w);
  o[4] = f2bf(b.x); o[5] = f2bf(b.y); o[6] = f2bf(b.z); o[7] = f2bf(b.w);
  return o;
}

// tanh via hardware exp2: tanh(x) = 1 - 2/(2^(2x*log2e)+1). Correct limits at +-inf.
__device__ __forceinline__ float fast_tanh(float x) {
  float e = __builtin_amdgcn_exp2f(x * 2.885390081777927f);
  return 1.0f - 2.0f * __builtin_amdgcn_rcpf(e + 1.0f);
}

__device__ __forceinline__ void gload16(const short* g, short* l) {
  __builtin_amdgcn_global_load_lds((const __attribute__((address_space(1))) void*)g,
                                   (__attribute__((address_space(3))) void*)l, 16, 0, 0);
}

// ---------------- kernel 1a: Ua_w f32 -> bf16 tile image ----------------
__global__ void k_convert_ua(const float* __restrict__ src, short* __restrict__ dst) {
  int idx = blockIdx.x * 256 + threadIdx.x;    // 262144 x 16B units (grid 1024)
  int unit = idx & 1023;
  int kts  = (idx >> 10) & 63;
  int nt   = idx >> 16;
  int row  = unit >> 2;
  int sl   = unit & 3;
  int q    = sl ^ ((row >> 1) & 3);
  const float* s = src + (size_t)(nt * 256 + row) * D2_ + kts * 32 + q * 8;
  f32x4 a = *(const f32x4*)s;
  f32x4 b = *(const f32x4*)(s + 4);
  *(short8*)(dst + (size_t)idx * 8) = cvt8(a, b);
}

// ---------------- kernel 1b: keys f32 -> bf16 tile image ----------------
__global__ void k_convert_keys(const float* __restrict__ src, short* __restrict__ dst) {
  int idx = blockIdx.x * 256 + threadIdx.x;    // 16777216 x 16B units (grid 65536)
  int unit = idx & 1023;
  int kts  = (idx >> 10) & 63;
  int mt   = idx >> 16;                        // 0..255
  int row  = unit >> 2;
  int sl   = unit & 3;
  int q    = sl ^ ((row >> 1) & 3);
  const float* s = src + (size_t)(mt * 256 + row) * D2_ + kts * 32 + q * 8;
  f32x4 a = *(const f32x4*)s;
  f32x4 b = *(const f32x4*)(s + 4);
  *(short8*)(dst + (size_t)idx * 8) = cvt8(a, b);
}

// ---------------- kernel 2: wqb[b][h] = q[b] . Wa_w[h] + Wa_b[h] + Ua_b[h] ----------------
__global__ void k_wq(const float* __restrict__ query, const float* __restrict__ Wa_w,
                     const float* __restrict__ Wa_b, const float* __restrict__ Ua_b,
                     float* __restrict__ wqb) {
  int b = blockIdx.x;       // 32
  int hc = blockIdx.y;      // 8
  int t = threadIdx.x;      // 256
  __shared__ float q[H_];
  for (int i = t; i < H_; i += 256) q[i] = query[(size_t)b * (4 * H_) + 3 * H_ + i];
  __syncthreads();
  int h = hc * 128 + (t >> 1);
  int kh = (t & 1) * 512;
  const float* wr = Wa_w + (size_t)h * H_ + kh;
  float acc = 0.f;
  #pragma unroll 8
  for (int k = 0; k < 512; k += 4) {
    f32x4 wv = *(const f32x4*)(wr + k);
    acc += wv.x * q[kh + k] + wv.y * q[kh + k + 1] + wv.z * q[kh + k + 2] + wv.w * q[kh + k + 3];
  }
  acc += __shfl_xor(acc, 1);
  if ((t & 1) == 0) wqb[b * H_ + h] = acc + Wa_b[h] + Ua_b[h];
}

// ---------------- kernel 3: fused GEMM (keys @ Ua^T) + tanh + Va-reduce ----------------
// A through LDS (triple-buffer, depth-2 gload_lds prefetch, counted vmcnt never 0
// steady-state). B (L2-resident, 4 MB) read DIRECTLY from global into registers,
// double-buffered bfX/bfY one kt ahead -> LDS pipe carries only A (64 reads + 16 KB
// writes per CU-kt < MFMA 1242 cyc) -> MFMA is the single critical path.
#define MCL16(mb, AF, BF)                                                                         \
  __builtin_amdgcn_s_setprio(1);                                                                  \
  _Pragma("unroll")                                                                               \
  for (int n = 0; n < 4; ++n) {                                                                   \
    _Pragma("unroll")                                                                             \
    for (int i = 0; i < 4; ++i)                                                                   \
      acc[(mb) + i][n] =                                                                          \
          __builtin_amdgcn_mfma_f32_16x16x32_bf16(AF[i], BF[n], acc[(mb) + i][n], 0, 0, 0);       \
  }                                                                                               \
  __builtin_amdgcn_s_setprio(0);

// One K-step: af ds_reads from As[cur]; B(kt+1)->BFN (global->reg); A(kt+2) gload;
// MFMA with BFC; counted vmcnt drains exactly A(kt+1) before the barrier.
#define KT_BODY(KT, BFC, BFN)                                                                     \
  {                                                                                               \
    const short* Ac = &As[cur][0];                                                                \
    _Pragma("unroll")                                                                             \
    for (int i = 0; i < 4; ++i) af0[i] = *(const short8*)&Ac[aoff + i * 512];                     \
    _Pragma("unroll")                                                                             \
    for (int i = 0; i < 4; ++i) af1[i] = *(const short8*)&Ac[aoff + 2048 + i * 512];              \
    if ((KT) + 1 < NKT) {                                                                         \
      const short* bp = bgf + (size_t)((KT) + 1) * TILE_SH;                                       \
      _Pragma("unroll")                                                                           \
      for (int n = 0; n < 4; ++n) BFN[n] = *(const short8*)(bp + n * 512);                        \
    }                                                                                             \
    if ((KT) + 2 < NKT) {                                                                         \
      int stg = cur + 2; if (stg >= 3) stg -= 3;                                                  \
      const short* an = abase + (size_t)((KT) + 2) * TILE_SH;                                     \
      gload16(an,        &As[stg][wu]);                                                           \
      gload16(an + 4096, &As[stg][4096 + wu]);                                                    \
    }                                                                                             \
    MCL16(0, af0, BFC)                                                                            \
    MCL16(4, af1, BFC)                                                                            \
    if ((KT) + 2 < NKT) {                                                                         \
      asm volatile("s_waitcnt vmcnt(6)" ::: "memory");                                            \
    } else if ((KT) + 1 < NKT) {                                                                  \
      asm volatile("s_waitcnt vmcnt(4)" ::: "memory");                                            \
    }                                                                                             \
    if ((KT) + 1 < NKT) __builtin_amdgcn_s_barrier();                                             \
    cur = (cur == 2) ? 0 : cur + 1;                                                               \
  }

__global__ __launch_bounds__(512, 2) void k_gemm_score(
    const short* __restrict__ keys_bf, const short* __restrict__ uab_t,
    const float* __restrict__ wqb, const float* __restrict__ va,
    float* __restrict__ scores_p) {
  __shared__ short As[3][TILE_SH];   // 3 x 16 KB (A only)

  // bijective XCD swizzle: the 4 nt-blocks of an mt adjacent on one XCD
  const int bid = blockIdx.x;
  const int g = (bid & 7) * 128 + (bid >> 3);
  const int mt = g >> 2;               // 0..255
  const int nt = g & 3;                // 0..3
  const int r0 = mt * BM;
  const int h0 = nt * BN;

  const int t = threadIdx.x;
  const int lane = t & 63;
  const int w = t >> 6;
  const int wm = w >> 2;               // 0..1 (128-row half)
  const int wn = w & 3;                // 0..3 (64-col quarter)

  f32x4 acc[8][4] = {};

  const short* abase = keys_bf + (size_t)mt * (NKT * TILE_SH) + t * 8;
  const int wu = w * 512;              // wave-uniform shorts (1 KB chunks per wave)

  // fragment read offsets (shorts); for 16-row frags (row>>1)&3 == (lr>>1)&3
  const int lr = lane & 15;
  const int lq = lane >> 4;
  const int slot = lq ^ ((lr >> 1) & 3);
  const int aoff = (wm * 128 + lr) * 32 + slot * 8;
  const int boff = (wn * 64 + lr) * 32 + slot * 8;
  const short* bgf = uab_t + (size_t)nt * (NKT * TILE_SH) + boff;   // per-lane B frag base

  short8 af0[4], af1[4], bfX[4], bfY[4];

  // ---- prologue: B(0) -> bfX; stage A(0) and A(1); drain B0+A0 only ----
  {
    #pragma unroll
    for (int n = 0; n < 4; ++n) bfX[n] = *(const short8*)(bgf + n * 512);
    gload16(abase,                  &As[0][wu]);
    gload16(abase + 4096,           &As[0][4096 + wu]);
    gload16(abase + TILE_SH,        &As[1][wu]);
    gload16(abase + TILE_SH + 4096, &As[1][4096 + wu]);
    asm volatile("s_waitcnt vmcnt(2)" ::: "memory");   // B0 + A(0) landed; A(1) in flight
    __builtin_amdgcn_s_barrier();
  }

  int cur = 0;
  #pragma unroll 1
  for (int ktp = 0; ktp < NKT / 2; ++ktp) {
    KT_BODY(2 * ktp,     bfX, bfY)
    KT_BODY(2 * ktp + 1, bfY, bfX)
  }

  // ---- epilogue: tanh + Va-weighted row-reduce ----
  // C/D layout: col = lane&15, row = (lane>>4)*4 + reg
  const int lgrp = lane >> 4;
  const int lc = lane & 15;
  float vah[4];
  #pragma unroll
  for (int n = 0; n < 4; ++n) vah[n] = va[h0 + wn * 64 + n * 16 + lc];
  #pragma unroll
  for (int m = 0; m < 8; ++m) {
    #pragma unroll
    for (int reg = 0; reg < 4; ++reg) {
      int row = wm * 128 + m * 16 + lgrp * 4 + reg;
      int r = r0 + row;
      int bb = r & (B_ - 1);
      const float* wrow = wqb + bb * H_ + h0 + wn * 64 + lc;
      float s = 0.f;
      #pragma unroll
      for (int n = 0; n < 4; ++n)
        s += vah[n] * fast_tanh(acc[m][n][reg] + wrow[n * 16]);
      s += __shfl_xor(s, 1);
      s += __shfl_xor(s, 2);
      s += __shfl_xor(s, 4);
      s += __shfl_xor(s, 8);
      if (lc == 0) scores_p[(size_t)r * 16 + nt * 4 + wn] = s;
    }
  }
}

// ---------------- fallback GEMM (reg-staged A from f32; used when ws too small) ----------------
__global__ __launch_bounds__(512, 2) void k_gemm_rs(
    const float* __restrict__ keys, const short* __restrict__ uab_t,
    const float* __restrict__ wqb, const float* __restrict__ va,
    float* __restrict__ scores_p) {
  __shared__ short As[2][TILE_SH];
  __shared__ short Bs[2][TILE_SH];
  const int bid = blockIdx.x;
  const int g = (bid & 7) * 128 + (bid >> 3);
  const int mt = g >> 2;
  const int nt = g & 3;
  const int r0 = mt * BM;
  const int h0 = nt * BN;
  const int t = threadIdx.x;
  const int lane = t & 63;
  const int w = t >> 6;
  const int wm = w >> 2;
  const int wn = w & 3;
  f32x4 acc[8][4] = {};
  const int arow = t >> 1;
  const int hh = t & 1;
  const float* abase = keys + (size_t)(r0 + arow) * D2_ + hh * 16;
  int awoff[2];
  #pragma unroll
  for (int j = 0; j < 2; ++j)
    awoff[j] = arow * 32 + (((2 * hh + j) ^ ((arow >> 1) & 3)) << 3);
  const short* bbase = uab_t + (size_t)nt * NKT * TILE_SH + t * 8;
  const int wu = w * 512;
  const int lr = lane & 15;
  const int lq = lane >> 4;
  const int slot = lq ^ ((lr >> 1) & 3);
  const int aoff = (wm * 128 + lr) * 32 + slot * 8;
  const int boff = (wn * 64 + lr) * 32 + slot * 8;
  short8 bf[4], af0[4], af1[4];
  {
    f32x4 v0 = *(const f32x4*)(abase);
    f32x4 v1 = *(const f32x4*)(abase + 4);
    f32x4 v2 = *(const f32x4*)(abase + 8);
    f32x4 v3 = *(const f32x4*)(abase + 12);
    *(short8*)&As[0][awoff[0]] = cvt8(v0, v1);
    *(short8*)&As[0][awoff[1]] = cvt8(v2, v3);
    gload16(bbase,        &Bs[0][wu]);
    gload16(bbase + 4096, &Bs[0][4096 + wu]);
    asm volatile("s_waitcnt vmcnt(0) lgkmcnt(0)" ::: "memory");
    __builtin_amdgcn_s_barrier();
  }
  #pragma unroll 1
  for (int kts = 0; kts < NKT; ++kts) {
    const int cb = kts & 1;
    const bool stage = (kts < NKT - 1);
    const float* anext = abase + (kts + 1) * BK;
    const short* bnext = bbase + (size_t)(kts + 1) * TILE_SH;
    short* Anb = &As[cb ^ 1][0];
    short* Bnb = &Bs[cb ^ 1][0];
    const short* Ac = As[cb];
    const short* Bc = Bs[cb];

    #pragma unroll
    for (int n = 0; n < 4; ++n) bf[n] = *(const short8*)&Bc[boff + n * 512];
    #pragma unroll
    for (int i = 0; i < 4; ++i) af0[i] = *(const short8*)&Ac[aoff + i * 512];
    #pragma unroll
    for (int i = 0; i < 4; ++i) af1[i] = *(const short8*)&Ac[aoff + 2048 + i * 512];
    f32x4 v0, v1, v2, v3;
    if (stage) {
      v0 = *(const f32x4*)(anext);
      v1 = *(const f32x4*)(anext + 4);
      v2 = *(const f32x4*)(anext + 8);
      v3 = *(const f32x4*)(anext + 12);
      gload16(bnext,        Bnb + wu);
      gload16(bnext + 4096, Bnb + 4096 + wu);
    }
    MCL16(0, af0, bf)
    MCL16(4, af1, bf)
    __builtin_amdgcn_s_barrier();
    if (stage) {
      *(short8*)&Anb[awoff[0]] = cvt8(v0, v1);
      *(short8*)&Anb[awoff[1]] = cvt8(v2, v3);
    }
    asm volatile("s_waitcnt vmcnt(0) lgkmcnt(0)" ::: "memory");
    __builtin_amdgcn_s_barrier();
  }
  const int lgrp = lane >> 4;
  const int lc = lane & 15;
  float vah[4];
  #pragma unroll
  for (int n = 0; n < 4; ++n) vah[n] = va[h0 + wn * 64 + n * 16 + lc];
  #pragma unroll
  for (int m = 0; m < 8; ++m) {
    #pragma unroll
    for (int reg = 0; reg < 4; ++reg) {
      int row = wm * 128 + m * 16 + lgrp * 4 + reg;
      int r = r0 + row;
      int bb = r & (B_ - 1);
      const float* wrow = wqb + bb * H_ + h0 + wn * 64 + lc;
      float s = 0.f;
      #pragma unroll
      for (int n = 0; n < 4; ++n)
        s += vah[n] * fast_tanh(acc[m][n][reg] + wrow[n * 16]);
      s += __shfl_xor(s, 1);
      s += __shfl_xor(s, 2);
      s += __shfl_xor(s, 4);
      s += __shfl_xor(s, 8);
      if (lc == 0) scores_p[(size_t)r * 16 + nt * 4 + wn] = s;
    }
  }
}

// ---------------- kernel 4: reduce 16 partials + softmax -> weights ----------------
__global__ void k_softmax(const float* __restrict__ scores_p, float* __restrict__ out) {
  int b = blockIdx.x;
  int t = threadIdx.x;
  __shared__ float sc[S_];
  __shared__ float red[4];
  float lmax = -3.4e38f;
  #pragma unroll
  for (int i = 0; i < 8; ++i) {
    int s = t + i * 256;
    const float* p = scores_p + ((size_t)s * B_ + b) * 16;
    f32x4 p0 = *(const f32x4*)p;
    f32x4 p1 = *(const f32x4*)(p + 4);
    f32x4 p2 = *(const f32x4*)(p + 8);
    f32x4 p3 = *(const f32x4*)(p + 12);
    f32x4 ps = p0 + p1 + p2 + p3;
    float v = ps.x + ps.y + ps.z + ps.w;
    sc[s] = v;
    lmax = fmaxf(lmax, v);
  }
  #pragma unroll
  for (int o = 32; o >= 1; o >>= 1) lmax = fmaxf(lmax, __shfl_xor(lmax, o));
  if ((t & 63) == 0) red[t >> 6] = lmax;
  __syncthreads();
  float gmax = fmaxf(fmaxf(red[0], red[1]), fmaxf(red[2], red[3]));
  __syncthreads();
  float lsum = 0.f;
  #pragma unroll
  for (int i = 0; i < 8; ++i) {
    int s = t + i * 256;
    float e = __builtin_amdgcn_exp2f((sc[s] - gmax) * 1.4426950408889634f);
    sc[s] = e;
    lsum += e;
  }
  #pragma unroll
  for (int o = 32; o >= 1; o >>= 1) lsum += __shfl_xor(lsum, o);
  if ((t & 63) == 0) red[t >> 6] = lsum;
  __syncthreads();
  float inv = 1.0f / (red[0] + red[1] + red[2] + red[3]);
  for (int i = 0; i < 8; ++i) {
    int s = t + i * 256;
    out[(size_t)65536 + b * S_ + s] = sc[s] * inv;
  }
}

// ---------------- kernel 5 (big path): ctx partials from bf16 tiles ----------------
// Grid (ktp=32, mtc=16). Thread (cg=t>>5, b=t&31): kts = ktp*2 + (cg>>2), q = cg&3,
// slot = q ^ ((b>>1)&3) (rows s8*32+b have (row>>1)&3 == (b>>1)&3).
__global__ __launch_bounds__(256) void k_ctx_partial_bf2(const short* __restrict__ keys_bf,
                                                         const float* __restrict__ wts,
                                                         float* __restrict__ cp) {
  const int ktp = blockIdx.x;   // 32
  const int mtc = blockIdx.y;   // 16
  const int t = threadIdx.x;    // 256
  const int cg = t >> 5;        // 0..7
  const int b = t & 31;
  const int kts = ktp * 2 + (cg >> 2);
  const int slot = (cg & 3) ^ ((b >> 1) & 3);
  const float* wbase = wts + (size_t)b * S_ + mtc * 128;
  f32x4 accA = {}, accB = {};
  #pragma unroll 2
  for (int c = 0; c < 16; ++c) {
    const short* tb = keys_bf + ((size_t)((mtc * 16 + c) * 64 + kts)) * TILE_SH + (slot << 3);
    f32x4 w0 = *(const f32x4*)(wbase + c * 8);
    f32x4 w1 = *(const f32x4*)(wbase + c * 8 + 4);
    float wg[8] = {w0.x, w0.y, w0.z, w0.w, w1.x, w1.y, w1.z, w1.w};
    #pragma unroll
    for (int s8 = 0; s8 < 8; ++s8) {
      short8 v = *(const short8*)(tb + (s8 * 32 + b) * 32);
      float wgt = wg[s8];
      accA.x += wgt * bf2f(v[0]); accA.y += wgt * bf2f(v[1]);
      accA.z += wgt * bf2f(v[2]); accA.w += wgt * bf2f(v[3]);
      accB.x += wgt * bf2f(v[4]); accB.y += wgt * bf2f(v[5]);
      accB.z += wgt * bf2f(v[6]); accB.w += wgt * bf2f(v[7]);
    }
  }
  float* o = cp + ((size_t)mtc * B_ + b) * D2_ + ktp * 64 + (cg & 3) * 8 + (cg >> 2) * 32;
  *(f32x4*)o = accA;
  *(f32x4*)(o + 4) = accB;
}

// ---------------- kernel 5 (fallback): ctx partials from f32 keys ----------------
__global__ void k_ctx_partial(const float* __restrict__ keys, const float* __restrict__ wts,
                              float* __restrict__ cp) {
  int b = blockIdx.x;
  int dc = blockIdx.y;
  int scn = blockIdx.z;
  int t = threadIdx.x;
  __shared__ float wl[256];
  int s0 = scn * 256;
  wl[t] = wts[b * S_ + s0 + t];
  __syncthreads();
  int d = dc * 1024 + t * 4;
  f32x4 acc = {};
  #pragma unroll 4
  for (int i = 0; i < 256; ++i) {
    int s = s0 + i;
    f32x4 kv = *(const f32x4*)(keys + ((size_t)s * B_ + b) * D2_ + d);
    acc += kv * wl[i];
  }
  *(f32x4*)(cp + ((size_t)scn * B_ + b) * D2_ + d) = acc;
}

// ---------------- kernel 6: reduce context partials ----------------
__global__ void k_ctx_reduce(const float* __restrict__ cp, float* __restrict__ out, int np) {
  int i = blockIdx.x * 256 + threadIdx.x;
  float s = 0.f;
  for (int j = 0; j < np; ++j) s += cp[(size_t)j * 65536 + i];
  out[i] = s;
}

extern "C" void kernel_launch(void* const* d_in, const int* in_sizes, int n_in,
                              void* d_out, int out_size, void* d_ws, size_t ws_size,
                              hipStream_t stream) {
  const float* query = (const float*)d_in[0];
  const float* keys  = (const float*)d_in[1];
  const float* Wa_w  = (const float*)d_in[2];
  const float* Wa_b  = (const float*)d_in[3];
  const float* Ua_w  = (const float*)d_in[4];
  const float* Ua_b  = (const float*)d_in[5];
  const float* Va_w  = (const float*)d_in[6];
  // Va_b (d_in[7]) intentionally unused: softmax is shift-invariant.
  float* out = (float*)d_out;
  char* ws = (char*)d_ws;

  const size_t KEYS_BF_BYTES = 268435456ull;  // 256 MiB
  const size_t TAIL = 16ull * 1024 * 1024;    // uab 4M + wqb 128K + sp 4M + cp 4M + pad
  bool big = ws_size >= KEYS_BF_BYTES + TAIL;

  if (big) {
    short* keys_bf = (short*)ws;
    char* base = ws + KEYS_BF_BYTES;
    short* uab_t = (short*)(base);
    float* wqb = (float*)(base + 4u * 1024 * 1024);
    float* sp  = (float*)(base + 4u * 1024 * 1024 + 128 * 1024);
    float* cp  = (float*)(base + 8u * 1024 * 1024 + 256 * 1024);   // 4 MB (16 partials)

    hipLaunchKernelGGL(k_convert_ua, dim3(1024), dim3(256), 0, stream, Ua_w, uab_t);
    hipLaunchKernelGGL(k_convert_keys, dim3(65536), dim3(256), 0, stream, keys, keys_bf);
    hipLaunchKernelGGL(k_wq, dim3(32, 8), dim3(256), 0, stream, query, Wa_w, Wa_b, Ua_b, wqb);
    hipLaunchKernelGGL(k_gemm_score, dim3(1024), dim3(512), 0, stream, keys_bf, uab_t, wqb, Va_w, sp);
    hipLaunchKernelGGL(k_softmax, dim3(32), dim3(256), 0, stream, sp, out);
    hipLaunchKernelGGL(k_ctx_partial_bf2, dim3(32, 16), dim3(256), 0, stream, keys_bf, out + 65536, cp);
    hipLaunchKernelGGL(k_ctx_reduce, dim3(256), dim3(256), 0, stream, cp, out, 16);
  } else {
    short* uab_t = (short*)(ws);
    float* wqb = (float*)(ws + 4u * 1024 * 1024);
    float* sp  = (float*)(ws + 4u * 1024 * 1024 + 128 * 1024);
    float* cp  = (float*)(ws + 8u * 1024 * 1024 + 256 * 1024);

    hipLaunchKernelGGL(k_convert_ua, dim3(1024), dim3(256), 0, stream, Ua_w, uab_t);
    hipLaunchKernelGGL(k_wq, dim3(32, 8), dim3(256), 0, stream, query, Wa_w, Wa_b, Ua_b, wqb);
    hipLaunchKernelGGL(k_gemm_rs, dim3(1024), dim3(512), 0, stream, keys, uab_t, wqb, Va_w, sp);
    hipLaunchKernelGGL(k_softmax, dim3(32), dim3(256), 0, stream, sp, out);
    hipLaunchKernelGGL(k_ctx_partial, dim3(32, 2, 8), dim3(256), 0, stream, keys, out + 65536, cp);
    hipLaunchKernelGGL(k_ctx_reduce, dim3(256), dim3(256), 0, stream, cp, out, 8);
  }
}

// Round 14
// 476.883 us; speedup vs baseline: 1.1289x; 1.1289x over previous
//
#include <hip/hip_runtime.h>
#include <hip/hip_bf16.h>

typedef __attribute__((ext_vector_type(4))) float f32x4;
typedef __attribute__((ext_vector_type(8))) short short8;

#define B_   32
#define S_   2048
#define H_   1024
#define D2_  2048   // 2H
#define BM   256
#define BN   256
#define BK   32
#define NKT  64        // D2_/BK
#define TILE_SH 8192   // shorts per 256x32 tile (16 KB)

// Tile image layout (keys_bf [mt 256][kts 64], uab_t [nt 4][kts 64]): per tile
// 256 rows x 4 slots x 16B; slot s' holds k-quarter q = s' ^ ((row>>1)&3);
// global k = kts*32 + q*8 + e.  Bank quads balanced for 16-row b128 reads.

// RNE f32 -> bf16
__device__ __forceinline__ short f2bf(float f) {
  unsigned u = __float_as_uint(f);
  u = (u + 0x7fffu + ((u >> 16) & 1u)) >> 16;
  return (short)u;
}

__device__ __forceinline__ float bf2f(short s) {
  return __uint_as_float(((unsigned)(unsigned short)s) << 16);
}

__device__ __forceinline__ short8 cvt8(f32x4 a, f32x4 b) {
  short8 o;
  o[0] = f2bf(a.x); o[1] = f2bf(a.y); o[2] = f2bf(a.z); o[3] = f2bf(a.w);
  o[4] = f2bf(b.x); o[5] = f2bf(b.y); o[6] = f2bf(b.z); o[7] = f2bf(b.w);
  return o;
}

// tanh via hardware exp2: tanh(x) = 1 - 2/(2^(2x*log2e)+1). Correct limits at +-inf.
__device__ __forceinline__ float fast_tanh(float x) {
  float e = __builtin_amdgcn_exp2f(x * 2.885390081777927f);
  return 1.0f - 2.0f * __builtin_amdgcn_rcpf(e + 1.0f);
}

__device__ __forceinline__ void gload16(const short* g, short* l) {
  __builtin_amdgcn_global_load_lds((const __attribute__((address_space(1))) void*)g,
                                   (__attribute__((address_space(3))) void*)l, 16, 0, 0);
}

// ---------------- kernel 1a: Ua_w f32 -> bf16 tile image ----------------
__global__ void k_convert_ua(const float* __restrict__ src, short* __restrict__ dst) {
  int idx = blockIdx.x * 256 + threadIdx.x;    // 262144 x 16B units (grid 1024)
  int unit = idx & 1023;
  int kts  = (idx >> 10) & 63;
  int nt   = idx >> 16;
  int row  = unit >> 2;
  int sl   = unit & 3;
  int q    = sl ^ ((row >> 1) & 3);
  const float* s = src + (size_t)(nt * 256 + row) * D2_ + kts * 32 + q * 8;
  f32x4 a = *(const f32x4*)s;
  f32x4 b = *(const f32x4*)(s + 4);
  *(short8*)(dst + (size_t)idx * 8) = cvt8(a, b);
}

// ---------------- kernel 1b: keys f32 -> bf16 tile image ----------------
__global__ void k_convert_keys(const float* __restrict__ src, short* __restrict__ dst) {
  int idx = blockIdx.x * 256 + threadIdx.x;    // 16777216 x 16B units (grid 65536)
  int unit = idx & 1023;
  int kts  = (idx >> 10) & 63;
  int mt   = idx >> 16;                        // 0..255
  int row  = unit >> 2;
  int sl   = unit & 3;
  int q    = sl ^ ((row >> 1) & 3);
  const float* s = src + (size_t)(mt * 256 + row) * D2_ + kts * 32 + q * 8;
  f32x4 a = *(const f32x4*)s;
  f32x4 b = *(const f32x4*)(s + 4);
  *(short8*)(dst + (size_t)idx * 8) = cvt8(a, b);
}

// ---------------- kernel 2: wqb[b][h] = q[b] . Wa_w[h] + Wa_b[h] + Ua_b[h] ----------------
__global__ void k_wq(const float* __restrict__ query, const float* __restrict__ Wa_w,
                     const float* __restrict__ Wa_b, const float* __restrict__ Ua_b,
                     float* __restrict__ wqb) {
  int b = blockIdx.x;       // 32
  int hc = blockIdx.y;      // 8
  int t = threadIdx.x;      // 256
  __shared__ float q[H_];
  for (int i = t; i < H_; i += 256) q[i] = query[(size_t)b * (4 * H_) + 3 * H_ + i];
  __syncthreads();
  int h = hc * 128 + (t >> 1);
  int kh = (t & 1) * 512;
  const float* wr = Wa_w + (size_t)h * H_ + kh;
  float acc = 0.f;
  #pragma unroll 8
  for (int k = 0; k < 512; k += 4) {
    f32x4 wv = *(const f32x4*)(wr + k);
    acc += wv.x * q[kh + k] + wv.y * q[kh + k + 1] + wv.z * q[kh + k + 2] + wv.w * q[kh + k + 3];
  }
  acc += __shfl_xor(acc, 1);
  if ((t & 1) == 0) wqb[b * H_ + h] = acc + Wa_b[h] + Ua_b[h];
}

// ---------------- kernel 3: fused GEMM (keys @ Ua^T) + tanh + Va-reduce ----------------
// BK=32, TRIPLE-buffered LDS (96 KB), depth-2 prefetch, counted vmcnt(4) steady state
// (never drains to 0 in the main loop), one barrier per K-tile. No manual lgkm gates:
// the compiler emits fine-grained lgkmcnt(N) so early MFMAs overlap remaining ds_reads.
#define MCL16(mb, AF)                                                                             \
  __builtin_amdgcn_s_setprio(1);                                                                  \
  _Pragma("unroll")                                                                               \
  for (int n = 0; n < 4; ++n) {                                                                   \
    _Pragma("unroll")                                                                             \
    for (int i = 0; i < 4; ++i)                                                                   \
      acc[(mb) + i][n] =                                                                          \
          __builtin_amdgcn_mfma_f32_16x16x32_bf16(AF[i], bf[n], acc[(mb) + i][n], 0, 0, 0);       \
  }                                                                                               \
  __builtin_amdgcn_s_setprio(0);

__global__ __launch_bounds__(512, 2) void k_gemm_score(
    const short* __restrict__ keys_bf, const short* __restrict__ uab_t,
    const float* __restrict__ wqb, const float* __restrict__ va,
    float* __restrict__ scores_p) {
  __shared__ short As[3][TILE_SH];   // 3 x 16 KB
  __shared__ short Bs[3][TILE_SH];   // 3 x 16 KB

  // bijective XCD swizzle: the 4 nt-blocks of an mt adjacent on one XCD
  const int bid = blockIdx.x;
  const int g = (bid & 7) * 128 + (bid >> 3);
  const int mt = g >> 2;               // 0..255
  const int nt = g & 3;                // 0..3
  const int r0 = mt * BM;
  const int h0 = nt * BN;

  const int t = threadIdx.x;
  const int lane = t & 63;
  const int w = t >> 6;
  const int wm = w >> 2;               // 0..1 (128-row half)
  const int wn = w & 3;                // 0..3 (64-col quarter)

  f32x4 acc[8][4] = {};

  const short* abase = keys_bf + (size_t)mt * (NKT * TILE_SH) + t * 8;
  const short* bbase = uab_t  + (size_t)nt * (NKT * TILE_SH) + t * 8;
  const int wu = w * 512;              // wave-uniform shorts (1 KB chunks per wave)

  // fragment read offsets (shorts); for 16-row frags (row>>1)&3 == (lr>>1)&3
  const int lr = lane & 15;
  const int lq = lane >> 4;
  const int slot = lq ^ ((lr >> 1) & 3);
  const int aoff = (wm * 128 + lr) * 32 + slot * 8;
  const int boff = (wn * 64 + lr) * 32 + slot * 8;

  // ---- prologue: stage tiles 0 and 1 ----
  {
    gload16(abase,                  &As[0][wu]);
    gload16(abase + 4096,           &As[0][4096 + wu]);
    gload16(bbase,                  &Bs[0][wu]);
    gload16(bbase + 4096,           &Bs[0][4096 + wu]);
    gload16(abase + TILE_SH,        &As[1][wu]);
    gload16(abase + TILE_SH + 4096, &As[1][4096 + wu]);
    gload16(bbase + TILE_SH,        &Bs[1][wu]);
    gload16(bbase + TILE_SH + 4096, &Bs[1][4096 + wu]);
    asm volatile("s_waitcnt vmcnt(4)" ::: "memory");   // tile 0 landed
    __builtin_amdgcn_s_barrier();
  }

  short8 bf[4], af0[4], af1[4];
  int cur = 0;

  #pragma unroll 1
  for (int kts = 0; kts < NKT; ++kts) {
    int stg = cur + 2; if (stg >= 3) stg -= 3;    // buffer for tile kts+2
    const short* Ac = &As[cur][0];
    const short* Bc = &Bs[cur][0];

    // 12 ds_reads of current tile (order: bf, af0, af1)
    #pragma unroll
    for (int n = 0; n < 4; ++n) bf[n] = *(const short8*)&Bc[boff + n * 512];
    #pragma unroll
    for (int i = 0; i < 4; ++i) af0[i] = *(const short8*)&Ac[aoff + i * 512];
    #pragma unroll
    for (int i = 0; i < 4; ++i) af1[i] = *(const short8*)&Ac[aoff + 2048 + i * 512];

    // depth-2 prefetch: stage tile kts+2 (its last readers finished before the
    // barrier that ended tile kts-1)
    if (kts < NKT - 2) {
      const short* an = abase + (size_t)(kts + 2) * TILE_SH;
      const short* bn = bbase + (size_t)(kts + 2) * TILE_SH;
      gload16(an,        &As[stg][wu]);
      gload16(an + 4096, &As[stg][4096 + wu]);
      gload16(bn,        &Bs[stg][wu]);
      gload16(bn + 4096, &Bs[stg][4096 + wu]);
    }

    // no manual lgkm gate: compiler inserts fine-grained lgkmcnt(N) per fragment,
    // letting the first MFMAs overlap the tail of the ds_read burst.
    MCL16(0, af0)
    MCL16(4, af1)

    // counted wait: ensure tile kts+1 (issued at kts-1, ~1 full tile of cover)
    // has landed before any wave reads it next iteration. Never 0 in steady state.
    if (kts < NKT - 2) {
      asm volatile("s_waitcnt vmcnt(4)" ::: "memory");
    } else if (kts == NKT - 2) {
      asm volatile("s_waitcnt vmcnt(0)" ::: "memory");
    }
    if (kts < NKT - 1) __builtin_amdgcn_s_barrier();

    cur = (cur == 2) ? 0 : cur + 1;
  }

  // ---- epilogue: tanh + Va-weighted row-reduce ----
  // C/D layout: col = lane&15, row = (lane>>4)*4 + reg
  const int lgrp = lane >> 4;
  const int lc = lane & 15;
  float vah[4];
  #pragma unroll
  for (int n = 0; n < 4; ++n) vah[n] = va[h0 + wn * 64 + n * 16 + lc];
  #pragma unroll
  for (int m = 0; m < 8; ++m) {
    #pragma unroll
    for (int reg = 0; reg < 4; ++reg) {
      int row = wm * 128 + m * 16 + lgrp * 4 + reg;
      int r = r0 + row;
      int bb = r & (B_ - 1);
      const float* wrow = wqb + bb * H_ + h0 + wn * 64 + lc;
      float s = 0.f;
      #pragma unroll
      for (int n = 0; n < 4; ++n)
        s += vah[n] * fast_tanh(acc[m][n][reg] + wrow[n * 16]);
      s += __shfl_xor(s, 1);
      s += __shfl_xor(s, 2);
      s += __shfl_xor(s, 4);
      s += __shfl_xor(s, 8);
      if (lc == 0) scores_p[(size_t)r * 16 + nt * 4 + wn] = s;
    }
  }
}

// ---------------- fallback GEMM (reg-staged A from f32; used when ws too small) ----------------
__global__ __launch_bounds__(512, 2) void k_gemm_rs(
    const float* __restrict__ keys, const short* __restrict__ uab_t,
    const float* __restrict__ wqb, const float* __restrict__ va,
    float* __restrict__ scores_p) {
  __shared__ short As[2][TILE_SH];
  __shared__ short Bs[2][TILE_SH];
  const int bid = blockIdx.x;
  const int g = (bid & 7) * 128 + (bid >> 3);
  const int mt = g >> 2;
  const int nt = g & 3;
  const int r0 = mt * BM;
  const int h0 = nt * BN;
  const int t = threadIdx.x;
  const int lane = t & 63;
  const int w = t >> 6;
  const int wm = w >> 2;
  const int wn = w & 3;
  f32x4 acc[8][4] = {};
  const int arow = t >> 1;
  const int hh = t & 1;
  const float* abase = keys + (size_t)(r0 + arow) * D2_ + hh * 16;
  int awoff[2];
  #pragma unroll
  for (int j = 0; j < 2; ++j)
    awoff[j] = arow * 32 + (((2 * hh + j) ^ ((arow >> 1) & 3)) << 3);
  const short* bbase = uab_t + (size_t)nt * NKT * TILE_SH + t * 8;
  const int wu = w * 512;
  const int lr = lane & 15;
  const int lq = lane >> 4;
  const int slot = lq ^ ((lr >> 1) & 3);
  const int aoff = (wm * 128 + lr) * 32 + slot * 8;
  const int boff = (wn * 64 + lr) * 32 + slot * 8;
  short8 bf[4], af0[4], af1[4];
  {
    f32x4 v0 = *(const f32x4*)(abase);
    f32x4 v1 = *(const f32x4*)(abase + 4);
    f32x4 v2 = *(const f32x4*)(abase + 8);
    f32x4 v3 = *(const f32x4*)(abase + 12);
    *(short8*)&As[0][awoff[0]] = cvt8(v0, v1);
    *(short8*)&As[0][awoff[1]] = cvt8(v2, v3);
    gload16(bbase,        &Bs[0][wu]);
    gload16(bbase + 4096, &Bs[0][4096 + wu]);
    asm volatile("s_waitcnt vmcnt(0) lgkmcnt(0)" ::: "memory");
    __builtin_amdgcn_s_barrier();
  }
  #pragma unroll 1
  for (int kts = 0; kts < NKT; ++kts) {
    const int cb = kts & 1;
    const bool stage = (kts < NKT - 1);
    const float* anext = abase + (kts + 1) * BK;
    const short* bnext = bbase + (size_t)(kts + 1) * TILE_SH;
    short* Anb = &As[cb ^ 1][0];
    short* Bnb = &Bs[cb ^ 1][0];
    const short* Ac = As[cb];
    const short* Bc = Bs[cb];

    #pragma unroll
    for (int n = 0; n < 4; ++n) bf[n] = *(const short8*)&Bc[boff + n * 512];
    #pragma unroll
    for (int i = 0; i < 4; ++i) af0[i] = *(const short8*)&Ac[aoff + i * 512];
    #pragma unroll
    for (int i = 0; i < 4; ++i) af1[i] = *(const short8*)&Ac[aoff + 2048 + i * 512];
    f32x4 v0, v1, v2, v3;
    if (stage) {
      v0 = *(const f32x4*)(anext);
      v1 = *(const f32x4*)(anext + 4);
      v2 = *(const f32x4*)(anext + 8);
      v3 = *(const f32x4*)(anext + 12);
      gload16(bnext,        Bnb + wu);
      gload16(bnext + 4096, Bnb + 4096 + wu);
    }
    MCL16(0, af0)
    MCL16(4, af1)
    __builtin_amdgcn_s_barrier();
    if (stage) {
      *(short8*)&Anb[awoff[0]] = cvt8(v0, v1);
      *(short8*)&Anb[awoff[1]] = cvt8(v2, v3);
    }
    asm volatile("s_waitcnt vmcnt(0) lgkmcnt(0)" ::: "memory");
    __builtin_amdgcn_s_barrier();
  }
  const int lgrp = lane >> 4;
  const int lc = lane & 15;
  float vah[4];
  #pragma unroll
  for (int n = 0; n < 4; ++n) vah[n] = va[h0 + wn * 64 + n * 16 + lc];
  #pragma unroll
  for (int m = 0; m < 8; ++m) {
    #pragma unroll
    for (int reg = 0; reg < 4; ++reg) {
      int row = wm * 128 + m * 16 + lgrp * 4 + reg;
      int r = r0 + row;
      int bb = r & (B_ - 1);
      const float* wrow = wqb + bb * H_ + h0 + wn * 64 + lc;
      float s = 0.f;
      #pragma unroll
      for (int n = 0; n < 4; ++n)
        s += vah[n] * fast_tanh(acc[m][n][reg] + wrow[n * 16]);
      s += __shfl_xor(s, 1);
      s += __shfl_xor(s, 2);
      s += __shfl_xor(s, 4);
      s += __shfl_xor(s, 8);
      if (lc == 0) scores_p[(size_t)r * 16 + nt * 4 + wn] = s;
    }
  }
}

// ---------------- kernel 4: reduce 16 partials + softmax -> weights ----------------
__global__ void k_softmax(const float* __restrict__ scores_p, float* __restrict__ out) {
  int b = blockIdx.x;
  int t = threadIdx.x;
  __shared__ float sc[S_];
  __shared__ float red[4];
  float lmax = -3.4e38f;
  #pragma unroll
  for (int i = 0; i < 8; ++i) {
    int s = t + i * 256;
    const float* p = scores_p + ((size_t)s * B_ + b) * 16;
    f32x4 p0 = *(const f32x4*)p;
    f32x4 p1 = *(const f32x4*)(p + 4);
    f32x4 p2 = *(const f32x4*)(p + 8);
    f32x4 p3 = *(const f32x4*)(p + 12);
    f32x4 ps = p0 + p1 + p2 + p3;
    float v = ps.x + ps.y + ps.z + ps.w;
    sc[s] = v;
    lmax = fmaxf(lmax, v);
  }
  #pragma unroll
  for (int o = 32; o >= 1; o >>= 1) lmax = fmaxf(lmax, __shfl_xor(lmax, o));
  if ((t & 63) == 0) red[t >> 6] = lmax;
  __syncthreads();
  float gmax = fmaxf(fmaxf(red[0], red[1]), fmaxf(red[2], red[3]));
  __syncthreads();
  float lsum = 0.f;
  #pragma unroll
  for (int i = 0; i < 8; ++i) {
    int s = t + i * 256;
    float e = __builtin_amdgcn_exp2f((sc[s] - gmax) * 1.4426950408889634f);
    sc[s] = e;
    lsum += e;
  }
  #pragma unroll
  for (int o = 32; o >= 1; o >>= 1) lsum += __shfl_xor(lsum, o);
  if ((t & 63) == 0) red[t >> 6] = lsum;
  __syncthreads();
  float inv = 1.0f / (red[0] + red[1] + red[2] + red[3]);
  for (int i = 0; i < 8; ++i) {
    int s = t + i * 256;
    out[(size_t)65536 + b * S_ + s] = sc[s] * inv;
  }
}

// ---------------- kernel 5 (big path): ctx partials from bf16 tiles ----------------
// Grid (ktp=32, mtc=16). Thread (cg=t>>5, b=t&31): kts = ktp*2 + (cg>>2), q = cg&3,
// slot = q ^ ((b>>1)&3) (rows s8*32+b have (row>>1)&3 == (b>>1)&3).
__global__ __launch_bounds__(256) void k_ctx_partial_bf2(const short* __restrict__ keys_bf,
                                                         const float* __restrict__ wts,
                                                         float* __restrict__ cp) {
  const int ktp = blockIdx.x;   // 32
  const int mtc = blockIdx.y;   // 16
  const int t = threadIdx.x;    // 256
  const int cg = t >> 5;        // 0..7
  const int b = t & 31;
  const int kts = ktp * 2 + (cg >> 2);
  const int slot = (cg & 3) ^ ((b >> 1) & 3);
  const float* wbase = wts + (size_t)b * S_ + mtc * 128;
  f32x4 accA = {}, accB = {};
  #pragma unroll 2
  for (int c = 0; c < 16; ++c) {
    const short* tb = keys_bf + ((size_t)((mtc * 16 + c) * 64 + kts)) * TILE_SH + (slot << 3);
    f32x4 w0 = *(const f32x4*)(wbase + c * 8);
    f32x4 w1 = *(const f32x4*)(wbase + c * 8 + 4);
    float wg[8] = {w0.x, w0.y, w0.z, w0.w, w1.x, w1.y, w1.z, w1.w};
    #pragma unroll
    for (int s8 = 0; s8 < 8; ++s8) {
      short8 v = *(const short8*)(tb + (s8 * 32 + b) * 32);
      float wgt = wg[s8];
      accA.x += wgt * bf2f(v[0]); accA.y += wgt * bf2f(v[1]);
      accA.z += wgt * bf2f(v[2]); accA.w += wgt * bf2f(v[3]);
      accB.x += wgt * bf2f(v[4]); accB.y += wgt * bf2f(v[5]);
      accB.z += wgt * bf2f(v[6]); accB.w += wgt * bf2f(v[7]);
    }
  }
  float* o = cp + ((size_t)mtc * B_ + b) * D2_ + ktp * 64 + (cg & 3) * 8 + (cg >> 2) * 32;
  *(f32x4*)o = accA;
  *(f32x4*)(o + 4) = accB;
}

// ---------------- kernel 5 (fallback): ctx partials from f32 keys ----------------
__global__ void k_ctx_partial(const float* __restrict__ keys, const float* __restrict__ wts,
                              float* __restrict__ cp) {
  int b = blockIdx.x;
  int dc = blockIdx.y;
  int scn = blockIdx.z;
  int t = threadIdx.x;
  __shared__ float wl[256];
  int s0 = scn * 256;
  wl[t] = wts[b * S_ + s0 + t];
  __syncthreads();
  int d = dc * 1024 + t * 4;
  f32x4 acc = {};
  #pragma unroll 4
  for (int i = 0; i < 256; ++i) {
    int s = s0 + i;
    f32x4 kv = *(const f32x4*)(keys + ((size_t)s * B_ + b) * D2_ + d);
    acc += kv * wl[i];
  }
  *(f32x4*)(cp + ((size_t)scn * B_ + b) * D2_ + d) = acc;
}

// ---------------- kernel 6: reduce context partials ----------------
__global__ void k_ctx_reduce(const float* __restrict__ cp, float* __restrict__ out, int np) {
  int i = blockIdx.x * 256 + threadIdx.x;
  float s = 0.f;
  for (int j = 0; j < np; ++j) s += cp[(size_t)j * 65536 + i];
  out[i] = s;
}

extern "C" void kernel_launch(void* const* d_in, const int* in_sizes, int n_in,
                              void* d_out, int out_size, void* d_ws, size_t ws_size,
                              hipStream_t stream) {
  const float* query = (const float*)d_in[0];
  const float* keys  = (const float*)d_in[1];
  const float* Wa_w  = (const float*)d_in[2];
  const float* Wa_b  = (const float*)d_in[3];
  const float* Ua_w  = (const float*)d_in[4];
  const float* Ua_b  = (const float*)d_in[5];
  const float* Va_w  = (const float*)d_in[6];
  // Va_b (d_in[7]) intentionally unused: softmax is shift-invariant.
  float* out = (float*)d_out;
  char* ws = (char*)d_ws;

  const size_t KEYS_BF_BYTES = 268435456ull;  // 256 MiB
  const size_t TAIL = 16ull * 1024 * 1024;    // uab 4M + wqb 128K + sp 4M + cp 4M + pad
  bool big = ws_size >= KEYS_BF_BYTES + TAIL;

  if (big) {
    short* keys_bf = (short*)ws;
    char* base = ws + KEYS_BF_BYTES;
    short* uab_t = (short*)(base);
    float* wqb = (float*)(base + 4u * 1024 * 1024);
    float* sp  = (float*)(base + 4u * 1024 * 1024 + 128 * 1024);
    float* cp  = (float*)(base + 8u * 1024 * 1024 + 256 * 1024);   // 4 MB (16 partials)

    hipLaunchKernelGGL(k_convert_ua, dim3(1024), dim3(256), 0, stream, Ua_w, uab_t);
    hipLaunchKernelGGL(k_convert_keys, dim3(65536), dim3(256), 0, stream, keys, keys_bf);
    hipLaunchKernelGGL(k_wq, dim3(32, 8), dim3(256), 0, stream, query, Wa_w, Wa_b, Ua_b, wqb);
    hipLaunchKernelGGL(k_gemm_score, dim3(1024), dim3(512), 0, stream, keys_bf, uab_t, wqb, Va_w, sp);
    hipLaunchKernelGGL(k_softmax, dim3(32), dim3(256), 0, stream, sp, out);
    hipLaunchKernelGGL(k_ctx_partial_bf2, dim3(32, 16), dim3(256), 0, stream, keys_bf, out + 65536, cp);
    hipLaunchKernelGGL(k_ctx_reduce, dim3(256), dim3(256), 0, stream, cp, out, 16);
  } else {
    short* uab_t = (short*)(ws);
    float* wqb = (float*)(ws + 4u * 1024 * 1024);
    float* sp  = (float*)(ws + 4u * 1024 * 1024 + 128 * 1024);
    float* cp  = (float*)(ws + 8u * 1024 * 1024 + 256 * 1024);

    hipLaunchKernelGGL(k_convert_ua, dim3(1024), dim3(256), 0, stream, Ua_w, uab_t);
    hipLaunchKernelGGL(k_wq, dim3(32, 8), dim3(256), 0, stream, query, Wa_w, Wa_b, Ua_b, wqb);
    hipLaunchKernelGGL(k_gemm_rs, dim3(1024), dim3(512), 0, stream, keys, uab_t, wqb, Va_w, sp);
    hipLaunchKernelGGL(k_softmax, dim3(32), dim3(256), 0, stream, sp, out);
    hipLaunchKernelGGL(k_ctx_partial, dim3(32, 2, 8), dim3(256), 0, stream, keys, out + 65536, cp);
    hipLaunchKernelGGL(k_ctx_reduce, dim3(256), dim3(256), 0, stream, cp, out, 8);
  }
}